// Round 6
// baseline (639.149 us; speedup 1.0000x reference)
//
#include <hip/hip_runtime.h>
#include <hip/hip_bf16.h>

#define NN 20000
#define EE 640000

typedef __attribute__((ext_vector_type(8))) short bf16x8;
typedef __attribute__((ext_vector_type(4))) float f32x4;

__device__ __forceinline__ ushort f2b(float f) {
    __hip_bfloat16 h = __float2bfloat16(f);
    return *(ushort*)&h;
}
__device__ __forceinline__ float b2f(ushort u) {
    __hip_bfloat16 h = *(__hip_bfloat16*)&u;
    return __bfloat162float(h);
}

// ---------------- CSR build ----------------

__global__ void init_cnt_kernel(int* __restrict__ cnt, int n) {
    int i = blockIdx.x * 256 + threadIdx.x;
    if (i < n) cnt[i] = 0;
}

__global__ void hist_kernel(const int* __restrict__ col, int* __restrict__ cnt, int e) {
    int i = blockIdx.x * 256 + threadIdx.x;
    if (i < e) atomicAdd(&cnt[col[i]], 1);
}

__global__ void dinv_kernel(const int* __restrict__ cnt, float* __restrict__ dinv, int n) {
    int i = blockIdx.x * 256 + threadIdx.x;
    if (i < n) dinv[i] = rsqrtf((float)(cnt[i] + 1));  // +1 self-loop; always > 0
}

// in-block exclusive scan helper (256 threads)
__device__ __forceinline__ int block_exscan(int v) {
    __shared__ int wsum[4];
    int tid = threadIdx.x, lane = tid & 63, w = tid >> 6;
    int x = v;
    #pragma unroll
    for (int d = 1; d < 64; d <<= 1) {
        int y = __shfl_up(x, d, 64);
        if (lane >= d) x += y;
    }
    if (lane == 63) wsum[w] = x;
    __syncthreads();
    if (tid == 0) {
        int s = 0;
        #pragma unroll
        for (int k = 0; k < 4; ++k) { int t = wsum[k]; wsum[k] = s; s += t; }
    }
    __syncthreads();
    return wsum[w] + x - v;
}

__global__ __launch_bounds__(256) void scan_p1_kernel(const int* __restrict__ cnt,
                                                      int* __restrict__ offs,
                                                      int* __restrict__ bsum, int n) {
    int i = blockIdx.x * 256 + threadIdx.x;
    int v = (i < n) ? cnt[i] : 0;
    int e = block_exscan(v);
    if (i < n) offs[i] = e;
    if (threadIdx.x == 255) bsum[blockIdx.x] = e + v;
}

__global__ __launch_bounds__(256) void scan_p2_kernel(int* __restrict__ bsum, int nblk) {
    int t = threadIdx.x;
    int v = (t < nblk) ? bsum[t] : 0;
    int e = block_exscan(v);
    if (t < nblk) bsum[t] = e;
}

__global__ __launch_bounds__(256) void scan_p3_kernel(int* __restrict__ offs,
                                                      const int* __restrict__ bsum,
                                                      int* __restrict__ cursor, int n) {
    int i = blockIdx.x * 256 + threadIdx.x;
    if (i < n) {
        int o = offs[i] + bsum[blockIdx.x];
        offs[i] = o;
        cursor[i] = o;
    }
}

__global__ void scatter_kernel(const int* __restrict__ row, const int* __restrict__ col,
                               const float* __restrict__ dinv, int* __restrict__ cursor,
                               int2* __restrict__ pair, int e) {
    int i = blockIdx.x * 256 + threadIdx.x;
    if (i >= e) return;
    int s = row[i], d = col[i];
    int pos = atomicAdd(&cursor[d], 1);
    int2 p;
    p.x = s;
    p.y = __float_as_int(dinv[s] * dinv[d]);
    pair[pos] = p;
}

// ---------------- degree-bucket node permutation ----------------
__global__ void zero256_kernel(int* __restrict__ a) {
    a[threadIdx.x] = 0;
}

__global__ void dhist_kernel(const int* __restrict__ cnt, int* __restrict__ dhist, int n) {
    int i = blockIdx.x * 256 + threadIdx.x;
    if (i < n) atomicAdd(&dhist[min(cnt[i], 255)], 1);
}

__global__ __launch_bounds__(256) void dscan_kernel(int* __restrict__ dhist,
                                                    int* __restrict__ dcur) {
    int t = threadIdx.x;
    int v = dhist[t];
    int e = block_exscan(v);
    dhist[t] = e;
    dcur[t] = e;
}

__global__ void dperm_kernel(const int* __restrict__ cnt, int* __restrict__ dcur,
                             int* __restrict__ perm, int n) {
    int i = blockIdx.x * 256 + threadIdx.x;
    if (i >= n) return;
    int pos = atomicAdd(&dcur[min(cnt[i], 255)], 1);
    perm[pos] = i;
}

// ---------------- weight prep: W [256][256] f32 -> Wt [256 col][768 kv] bf16 ----------------
__global__ __launch_bounds__(256) void wprep_kernel(const float* __restrict__ W,
                                                    ushort* __restrict__ Wt) {
    int col = blockIdx.x;
    for (int kv = threadIdx.x; kv < 768; kv += 256) {
        int k = kv & 255;
        float w = W[(size_t)k * 256 + col];
        ushort hi = f2b(w);
        ushort out = (kv < 256 || kv >= 512) ? hi : f2b(w - b2f(hi));
        Wt[(size_t)col * 768 + kv] = out;
    }
}

// ---------------- aggregation v6: chunked + degree-sorted + 4-deep unroll ----------------
// h row-major [n][256]. chunk = bid&7 (XCD-pinned 32-feat slice). Block: 4 waves x 8 nodes.
// Lane: g = lane>>3 (node in wave), fsub = lane&7 (float4 within chunk).
// Nodes taken in degree-sorted order via perm -> wave-uniform degree.
// Output: a2 [n][512] bf16 — cols 0..255 hi, 256..511 lo.
__global__ __launch_bounds__(256) void agg_kernel(
    const float* __restrict__ h,
    const int* __restrict__ offs, const int* __restrict__ cnt,
    const int2* __restrict__ pair, const int* __restrict__ perm,
    const float* __restrict__ dinv,
    ushort* __restrict__ a2, int n) {
    int chunk = blockIdx.x & 7;
    int wid = threadIdx.x >> 6;
    int lane = threadIdx.x & 63;
    int g = lane >> 3, fsub = lane & 7;
    int idx = (blockIdx.x >> 3) * 32 + wid * 8 + g;   // n % 32 == 0, in range
    int node = perm[idx];
    const float* base = h + chunk * 32 + fsub * 4;
    const unsigned long long* pq = (const unsigned long long*)pair;

    int beg = offs[node], num = cnt[node];
    int maxnum = num;
    #pragma unroll
    for (int d = 8; d < 64; d <<= 1)
        maxnum = max(maxnum, __shfl_xor(maxnum, d, 64));

    float4 acc = {0.f, 0.f, 0.f, 0.f};
    for (int j = 0; j < maxnum; j += 4) {
        bool p0 = j < num, p1 = j + 1 < num, p2 = j + 2 < num, p3 = j + 3 < num;
        unsigned long long q0 = __builtin_nontemporal_load(pq + (p0 ? beg + j     : beg));
        unsigned long long q1 = __builtin_nontemporal_load(pq + (p1 ? beg + j + 1 : beg));
        unsigned long long q2 = __builtin_nontemporal_load(pq + (p2 ? beg + j + 2 : beg));
        unsigned long long q3 = __builtin_nontemporal_load(pq + (p3 ? beg + j + 3 : beg));
        int s0 = (int)(q0 & 0xffffffffu), s1 = (int)(q1 & 0xffffffffu);
        int s2 = (int)(q2 & 0xffffffffu), s3 = (int)(q3 & 0xffffffffu);
        float m0 = p0 ? __int_as_float((int)(q0 >> 32)) : 0.f;
        float m1 = p1 ? __int_as_float((int)(q1 >> 32)) : 0.f;
        float m2 = p2 ? __int_as_float((int)(q2 >> 32)) : 0.f;
        float m3 = p3 ? __int_as_float((int)(q3 >> 32)) : 0.f;
        float4 v0 = *(const float4*)(base + (size_t)s0 * 256);
        float4 v1 = *(const float4*)(base + (size_t)s1 * 256);
        float4 v2 = *(const float4*)(base + (size_t)s2 * 256);
        float4 v3 = *(const float4*)(base + (size_t)s3 * 256);
        acc.x = fmaf(m0, v0.x, acc.x); acc.y = fmaf(m0, v0.y, acc.y);
        acc.z = fmaf(m0, v0.z, acc.z); acc.w = fmaf(m0, v0.w, acc.w);
        acc.x = fmaf(m1, v1.x, acc.x); acc.y = fmaf(m1, v1.y, acc.y);
        acc.z = fmaf(m1, v1.z, acc.z); acc.w = fmaf(m1, v1.w, acc.w);
        acc.x = fmaf(m2, v2.x, acc.x); acc.y = fmaf(m2, v2.y, acc.y);
        acc.z = fmaf(m2, v2.z, acc.z); acc.w = fmaf(m2, v2.w, acc.w);
        acc.x = fmaf(m3, v3.x, acc.x); acc.y = fmaf(m3, v3.y, acc.y);
        acc.z = fmaf(m3, v3.z, acc.z); acc.w = fmaf(m3, v3.w, acc.w);
    }

    float di = dinv[node];
    float sn = di * di;
    float4 self = *(const float4*)(base + (size_t)node * 256);
    acc.x = fmaf(sn, self.x, acc.x); acc.y = fmaf(sn, self.y, acc.y);
    acc.z = fmaf(sn, self.z, acc.z); acc.w = fmaf(sn, self.w, acc.w);

    int feat = chunk * 32 + fsub * 4;
    ushort4 hi, lo;
    hi.x = f2b(acc.x); lo.x = f2b(acc.x - b2f(hi.x));
    hi.y = f2b(acc.y); lo.y = f2b(acc.y - b2f(hi.y));
    hi.z = f2b(acc.z); lo.z = f2b(acc.z - b2f(hi.z));
    hi.w = f2b(acc.w); lo.w = f2b(acc.w - b2f(hi.w));
    *(ushort4*)(a2 + (size_t)node * 512 + feat)       = hi;
    *(ushort4*)(a2 + (size_t)node * 512 + 256 + feat) = lo;
}

// ---------------- bf16 MFMA GEMM: C = A'' @ W'' (+bias, opt ReLU), 128x128 tile ----------------
template<bool RELU>
__global__ __launch_bounds__(256) void gemm_mfma_kernel(
    const ushort* __restrict__ A2, const ushort* __restrict__ Wt,
    const float* __restrict__ bias, float* __restrict__ C, int n) {
    __shared__ ushort Ast[128][72];
    __shared__ ushort Bst[128][72];
    int tid = threadIdx.x;
    int lane = tid & 63, wid = tid >> 6;
    int rowbase = blockIdx.x * 128;
    int colbase = blockIdx.y * 128;
    int awr = (wid >> 1) * 64;
    int bwc = (wid & 1) * 64;

    f32x4 zero = {0.f, 0.f, 0.f, 0.f};
    f32x4 acc[4][4];
    #pragma unroll
    for (int m = 0; m < 4; ++m)
        #pragma unroll
        for (int nn = 0; nn < 4; ++nn) acc[m][nn] = zero;

    int rS = tid >> 1;                 // 0..127
    int sBase = (tid & 1) * 32;        // half-row of 64 shorts
    int grA = min(rowbase + rS, n - 1);
    const ushort* aRow = A2 + (size_t)grA * 512;
    const ushort* bRow = Wt + (size_t)(colbase + rS) * 768;

    for (int kt = 0; kt < 12; ++kt) {
        int kv0 = kt * 64;
        int acol0 = (kv0 < 256) ? kv0 : kv0 - 256;
        #pragma unroll
        for (int q = 0; q < 4; ++q)
            *(float4*)(&Ast[rS][sBase + q * 8]) =
                *(const float4*)(aRow + acol0 + sBase + q * 8);
        #pragma unroll
        for (int q = 0; q < 4; ++q)
            *(float4*)(&Bst[rS][sBase + q * 8]) =
                *(const float4*)(bRow + kv0 + sBase + q * 8);
        __syncthreads();
        #pragma unroll
        for (int kk = 0; kk < 2; ++kk) {
            int ko = kk * 32 + (lane >> 4) * 8;
            bf16x8 af[4], bf[4];
            #pragma unroll
            for (int m = 0; m < 4; ++m)
                af[m] = *(const bf16x8*)&Ast[awr + m * 16 + (lane & 15)][ko];
            #pragma unroll
            for (int nn = 0; nn < 4; ++nn)
                bf[nn] = *(const bf16x8*)&Bst[bwc + nn * 16 + (lane & 15)][ko];
            #pragma unroll
            for (int m = 0; m < 4; ++m)
                #pragma unroll
                for (int nn = 0; nn < 4; ++nn)
                    acc[m][nn] = __builtin_amdgcn_mfma_f32_16x16x32_bf16(
                        af[m], bf[nn], acc[m][nn], 0, 0, 0);
        }
        __syncthreads();
    }

    #pragma unroll
    for (int nn = 0; nn < 4; ++nn) {
        int col = colbase + bwc + nn * 16 + (lane & 15);
        float bv = bias[col];
        #pragma unroll
        for (int m = 0; m < 4; ++m) {
            int grow0 = rowbase + awr + m * 16 + ((lane >> 4) << 2);
            f32x4 v = acc[m][nn];
            #pragma unroll
            for (int r = 0; r < 4; ++r) {
                int row = grow0 + r;
                if (row < n) {
                    float val = v[r] + bv;
                    if (RELU) val = fmaxf(val, 0.f);
                    C[(size_t)row * 256 + col] = val;
                }
            }
        }
    }
}

// ---------------- final projection: out[i] = h3[i,:] . Wout + bout ----------------
__global__ __launch_bounds__(256) void out_kernel(
    const float* __restrict__ h3, const float* __restrict__ Wout,
    const float* __restrict__ bout, float* __restrict__ out, int n) {
    int node = blockIdx.x * 4 + (threadIdx.x >> 6);
    int lane = threadIdx.x & 63;
    if (node >= n) return;
    float4 v = ((const float4*)(h3 + (size_t)node * 256))[lane];
    float4 w = ((const float4*)Wout)[lane];
    float sum = v.x * w.x + v.y * w.y + v.z * w.z + v.w * w.w;
    #pragma unroll
    for (int d = 32; d > 0; d >>= 1) sum += __shfl_down(sum, d, 64);
    if (lane == 0) out[node] = sum + bout[0];
}

extern "C" void kernel_launch(void* const* d_in, const int* in_sizes, int n_in,
                              void* d_out, int out_size, void* d_ws, size_t ws_size,
                              hipStream_t stream) {
    const int n = NN, e = EE;
    const float* x    = (const float*)d_in[0];
    const int*   eidx = (const int*)d_in[1];
    const float* W1   = (const float*)d_in[2];
    const float* b1   = (const float*)d_in[3];
    const float* Wh   = (const float*)d_in[4];
    const float* bh   = (const float*)d_in[5];
    const float* W2   = (const float*)d_in[6];
    const float* b2   = (const float*)d_in[7];
    const float* Wout = (const float*)d_in[8];
    const float* bout = (const float*)d_in[9];
    const int* row = eidx;        // sources
    const int* col = eidx + e;    // destinations

    char* ws = (char*)d_ws;
    int*    cnt     = (int*)ws;    ws += (size_t)n * 4;
    int*    offs    = (int*)ws;    ws += (size_t)n * 4;
    int*    cursor  = (int*)ws;    ws += (size_t)n * 4;
    float*  dinv    = (float*)ws;  ws += (size_t)n * 4;
    int*    perm    = (int*)ws;    ws += (size_t)n * 4;
    int*    bsum    = (int*)ws;    ws += (size_t)256 * 4;
    int*    dhist   = (int*)ws;    ws += (size_t)256 * 4;
    int*    dcur    = (int*)ws;    ws += (size_t)256 * 4;
    int2*   pair    = (int2*)ws;   ws += (size_t)e * 8;
    float*  buf     = (float*)ws;  ws += (size_t)n * 256 * 4;   // hidden state [n][256]
    ushort* a2      = (ushort*)ws; ws += (size_t)n * 512 * 2;   // A'' hi|lo [n][512]
    ushort* wt1     = (ushort*)ws; ws += (size_t)256 * 768 * 2;
    ushort* wt2     = (ushort*)ws; ws += (size_t)256 * 768 * 2;
    ushort* wt3     = (ushort*)ws; ws += (size_t)256 * 768 * 2;

    float* outv = (float*)d_out;
    float* h3   = (float*)d_out + n;

    int nb_n = (n + 255) / 256;     // 79
    int nb_e = (e + 255) / 256;

    // CSR build
    init_cnt_kernel<<<nb_n, 256, 0, stream>>>(cnt, n);
    hist_kernel<<<nb_e, 256, 0, stream>>>(col, cnt, e);
    dinv_kernel<<<nb_n, 256, 0, stream>>>(cnt, dinv, n);
    scan_p1_kernel<<<nb_n, 256, 0, stream>>>(cnt, offs, bsum, n);
    scan_p2_kernel<<<1, 256, 0, stream>>>(bsum, nb_n);
    scan_p3_kernel<<<nb_n, 256, 0, stream>>>(offs, bsum, cursor, n);
    scatter_kernel<<<nb_e, 256, 0, stream>>>(row, col, dinv, cursor, pair, e);

    // degree-bucket permutation (equal-degree nodes grouped -> uniform waves)
    zero256_kernel<<<1, 256, 0, stream>>>(dhist);
    dhist_kernel<<<nb_n, 256, 0, stream>>>(cnt, dhist, n);
    dscan_kernel<<<1, 256, 0, stream>>>(dhist, dcur);
    dperm_kernel<<<nb_n, 256, 0, stream>>>(cnt, dcur, perm, n);

    // weight prep
    wprep_kernel<<<256, 256, 0, stream>>>(W1, wt1);
    wprep_kernel<<<256, 256, 0, stream>>>(Wh, wt2);
    wprep_kernel<<<256, 256, 0, stream>>>(W2, wt3);

    int agrid = (n / 32) * 8;          // 5000 blocks: chunk = bid&7, nodegroup = bid>>3
    dim3 ggrid((n + 127) / 128, 2);    // (157, 2)

    // layer 1 (agg reads x directly)
    agg_kernel<<<agrid, 256, 0, stream>>>(x, offs, cnt, pair, perm, dinv, a2, n);
    gemm_mfma_kernel<true><<<ggrid, 256, 0, stream>>>(a2, wt1, b1, buf, n);
    // layer 2
    agg_kernel<<<agrid, 256, 0, stream>>>(buf, offs, cnt, pair, perm, dinv, a2, n);
    gemm_mfma_kernel<true><<<ggrid, 256, 0, stream>>>(a2, wt2, bh, buf, n);
    // layer 3 -> h3 straight into d_out
    agg_kernel<<<agrid, 256, 0, stream>>>(buf, offs, cnt, pair, perm, dinv, a2, n);
    gemm_mfma_kernel<false><<<ggrid, 256, 0, stream>>>(a2, wt3, b2, h3, n);
    // decoder
    out_kernel<<<(n + 3) / 4, 256, 0, stream>>>(h3, Wout, bout, outv, n);
}

// Round 7
// 435.664 us; speedup vs baseline: 1.4671x; 1.4671x over previous
//
#include <hip/hip_runtime.h>
#include <hip/hip_bf16.h>

#define NN 20000
#define EE 640000

typedef __attribute__((ext_vector_type(8))) short bf16x8;
typedef __attribute__((ext_vector_type(4))) float f32x4;

__device__ __forceinline__ ushort f2b(float f) {
    __hip_bfloat16 h = __float2bfloat16(f);
    return *(ushort*)&h;
}
__device__ __forceinline__ float b2f(ushort u) {
    __hip_bfloat16 h = *(__hip_bfloat16*)&u;
    return __bfloat162float(h);
}

// accumulate 8 bf16 feats (one 16B vector) scaled by m into acc[8]
__device__ __forceinline__ void acc8(float m, bf16x8 v, float* acc) {
    union { bf16x8 v; unsigned u[4]; } t;
    t.v = v;
    #pragma unroll
    for (int k = 0; k < 4; ++k) {
        acc[2 * k]     = fmaf(m, __uint_as_float(t.u[k] << 16), acc[2 * k]);
        acc[2 * k + 1] = fmaf(m, __uint_as_float(t.u[k] & 0xffff0000u), acc[2 * k + 1]);
    }
}

// ---------------- CSR build ----------------

__global__ void init_cnt_kernel(int* __restrict__ cnt, int n) {
    int i = blockIdx.x * 256 + threadIdx.x;
    if (i < n) cnt[i] = 0;
}

__global__ void hist_kernel(const int* __restrict__ col, int* __restrict__ cnt, int e) {
    int i = blockIdx.x * 256 + threadIdx.x;
    if (i < e) atomicAdd(&cnt[col[i]], 1);
}

__global__ void dinv_kernel(const int* __restrict__ cnt, float* __restrict__ dinv, int n) {
    int i = blockIdx.x * 256 + threadIdx.x;
    if (i < n) dinv[i] = rsqrtf((float)(cnt[i] + 1));  // +1 self-loop; always > 0
}

__device__ __forceinline__ int block_exscan(int v) {
    __shared__ int wsum[4];
    int tid = threadIdx.x, lane = tid & 63, w = tid >> 6;
    int x = v;
    #pragma unroll
    for (int d = 1; d < 64; d <<= 1) {
        int y = __shfl_up(x, d, 64);
        if (lane >= d) x += y;
    }
    if (lane == 63) wsum[w] = x;
    __syncthreads();
    if (tid == 0) {
        int s = 0;
        #pragma unroll
        for (int k = 0; k < 4; ++k) { int t = wsum[k]; wsum[k] = s; s += t; }
    }
    __syncthreads();
    return wsum[w] + x - v;
}

__global__ __launch_bounds__(256) void scan_p1_kernel(const int* __restrict__ cnt,
                                                      int* __restrict__ offs,
                                                      int* __restrict__ bsum, int n) {
    int i = blockIdx.x * 256 + threadIdx.x;
    int v = (i < n) ? cnt[i] : 0;
    int e = block_exscan(v);
    if (i < n) offs[i] = e;
    if (threadIdx.x == 255) bsum[blockIdx.x] = e + v;
}

__global__ __launch_bounds__(256) void scan_p2_kernel(int* __restrict__ bsum, int nblk) {
    int t = threadIdx.x;
    int v = (t < nblk) ? bsum[t] : 0;
    int e = block_exscan(v);
    if (t < nblk) bsum[t] = e;
}

__global__ __launch_bounds__(256) void scan_p3_kernel(int* __restrict__ offs,
                                                      const int* __restrict__ bsum,
                                                      int* __restrict__ cursor, int n) {
    int i = blockIdx.x * 256 + threadIdx.x;
    if (i < n) {
        int o = offs[i] + bsum[blockIdx.x];
        offs[i] = o;
        cursor[i] = o;
    }
}

__global__ void scatter_kernel(const int* __restrict__ row, const int* __restrict__ col,
                               const float* __restrict__ dinv, int* __restrict__ cursor,
                               int2* __restrict__ pair, int e) {
    int i = blockIdx.x * 256 + threadIdx.x;
    if (i >= e) return;
    int s = row[i], d = col[i];
    int pos = atomicAdd(&cursor[d], 1);
    int2 p;
    p.x = s;
    p.y = __float_as_int(dinv[s] * dinv[d]);
    pair[pos] = p;
}

// ---------------- x f32 -> bf16 ----------------
__global__ __launch_bounds__(256) void cvt_kernel(const float* __restrict__ x,
                                                  ushort* __restrict__ xb, int total8) {
    int i = blockIdx.x * 256 + threadIdx.x;   // per 8 elements
    if (i >= total8) return;
    float4 a = ((const float4*)x)[2 * i];
    float4 b = ((const float4*)x)[2 * i + 1];
    union { bf16x8 v; ushort s[8]; } o;
    o.s[0] = f2b(a.x); o.s[1] = f2b(a.y); o.s[2] = f2b(a.z); o.s[3] = f2b(a.w);
    o.s[4] = f2b(b.x); o.s[5] = f2b(b.y); o.s[6] = f2b(b.z); o.s[7] = f2b(b.w);
    ((bf16x8*)xb)[i] = o.v;
}

// ---------------- weight prep: W [256][256] f32 -> Wt [256 col][768 kv] bf16 ----------------
__global__ __launch_bounds__(256) void wprep_kernel(const float* __restrict__ W,
                                                    ushort* __restrict__ Wt) {
    int col = blockIdx.x;
    for (int kv = threadIdx.x; kv < 768; kv += 256) {
        int k = kv & 255;
        float w = W[(size_t)k * 256 + col];
        ushort hi = f2b(w);
        ushort out = (kv < 256 || kv >= 512) ? hi : f2b(w - b2f(hi));
        Wt[(size_t)col * 768 + kv] = out;
    }
}

// ---------------- aggregation v7: bf16 gathers, wave per node, 64-feat chunks ----------------
// hb bf16 [n][256]. chunk = bid&3 (64 feats, slice 2.56MB L2-fit). 4 waves = 4 nodes/block.
// Lane: esub = lane>>3 (8 edges in flight per step), fsub = lane&7 (bf16x8 within chunk).
// 4-deep unroll -> 32 edges in flight. Output a2 [n][512] bf16 hi|lo.
__global__ __launch_bounds__(256) void agg_kernel(
    const ushort* __restrict__ hb,
    const int* __restrict__ offs, const int* __restrict__ cnt,
    const int2* __restrict__ pair,
    const float* __restrict__ dinv,
    ushort* __restrict__ a2, int n) {
    int chunk = blockIdx.x & 3;
    int node = (blockIdx.x >> 2) * 4 + (threadIdx.x >> 6);
    int lane = threadIdx.x & 63;
    int esub = lane >> 3, fsub = lane & 7;
    const ushort* base = hb + chunk * 64 + fsub * 8;
    const unsigned long long* pq = (const unsigned long long*)pair;

    int beg = offs[node], num = cnt[node];
    float acc[8] = {};

    for (int j = 0; j < num; j += 32) {
        int i0 = j + esub, i1 = j + 8 + esub, i2 = j + 16 + esub, i3 = j + 24 + esub;
        bool p0 = i0 < num, p1 = i1 < num, p2 = i2 < num, p3 = i3 < num;
        unsigned long long q0 = pq[p0 ? beg + i0 : beg];
        unsigned long long q1 = pq[p1 ? beg + i1 : beg];
        unsigned long long q2 = pq[p2 ? beg + i2 : beg];
        unsigned long long q3 = pq[p3 ? beg + i3 : beg];
        int s0 = (int)(q0 & 0xffffffffu), s1 = (int)(q1 & 0xffffffffu);
        int s2 = (int)(q2 & 0xffffffffu), s3 = (int)(q3 & 0xffffffffu);
        float m0 = p0 ? __int_as_float((int)(q0 >> 32)) : 0.f;
        float m1 = p1 ? __int_as_float((int)(q1 >> 32)) : 0.f;
        float m2 = p2 ? __int_as_float((int)(q2 >> 32)) : 0.f;
        float m3 = p3 ? __int_as_float((int)(q3 >> 32)) : 0.f;
        bf16x8 v0 = *(const bf16x8*)(base + (size_t)s0 * 256);
        bf16x8 v1 = *(const bf16x8*)(base + (size_t)s1 * 256);
        bf16x8 v2 = *(const bf16x8*)(base + (size_t)s2 * 256);
        bf16x8 v3 = *(const bf16x8*)(base + (size_t)s3 * 256);
        acc8(m0, v0, acc);
        acc8(m1, v1, acc);
        acc8(m2, v2, acc);
        acc8(m3, v3, acc);
    }

    // all-reduce across the 8 esub groups
    #pragma unroll
    for (int d = 8; d < 64; d <<= 1)
        #pragma unroll
        for (int k = 0; k < 8; ++k)
            acc[k] += __shfl_xor(acc[k], d, 64);

    if (esub == 0) {   // lanes 0..7 hold fsub 0..7
        float di = dinv[node];
        bf16x8 sv = *(const bf16x8*)(base + (size_t)node * 256);
        acc8(di * di, sv, acc);
        int feat = chunk * 64 + fsub * 8;
        union { bf16x8 v; ushort s[8]; } hi, lo;
        #pragma unroll
        for (int k = 0; k < 8; ++k) {
            hi.s[k] = f2b(acc[k]);
            lo.s[k] = f2b(acc[k] - b2f(hi.s[k]));
        }
        *(bf16x8*)(a2 + (size_t)node * 512 + feat)       = hi.v;
        *(bf16x8*)(a2 + (size_t)node * 512 + 256 + feat) = lo.v;
    }
}

// ---------------- bf16 MFMA GEMM, 128x128 tile, reg double-buffered staging ----------------
// C = A''@W'' + bias (opt ReLU). Output f32 (layer 3) or bf16 (layers 1-2).
template<bool RELU, bool BF16OUT>
__global__ __launch_bounds__(256) void gemm_mfma_kernel(
    const ushort* __restrict__ A2, const ushort* __restrict__ Wt,
    const float* __restrict__ bias, void* __restrict__ Cout, int n) {
    __shared__ ushort Ast[128][72];
    __shared__ ushort Bst[128][72];
    int tid = threadIdx.x;
    int lane = tid & 63, wid = tid >> 6;
    int rowbase = blockIdx.x * 128;
    int colbase = blockIdx.y * 128;
    int awr = (wid >> 1) * 64;
    int bwc = (wid & 1) * 64;

    f32x4 zero = {0.f, 0.f, 0.f, 0.f};
    f32x4 acc[4][4];
    #pragma unroll
    for (int m = 0; m < 4; ++m)
        #pragma unroll
        for (int nn = 0; nn < 4; ++nn) acc[m][nn] = zero;

    int rS = tid >> 1;                 // 0..127
    int sBase = (tid & 1) * 32;        // half-row of 64 shorts
    int grA = min(rowbase + rS, n - 1);
    const ushort* aRow = A2 + (size_t)grA * 512;
    const ushort* bRow = Wt + (size_t)(colbase + rS) * 768;

    float4 ra[4], rb[4];
    auto load_regs = [&](int kt) {
        int kv0 = kt * 64;
        int acol0 = (kv0 < 256) ? kv0 : kv0 - 256;
        #pragma unroll
        for (int q = 0; q < 4; ++q)
            ra[q] = *(const float4*)(aRow + acol0 + sBase + q * 8);
        #pragma unroll
        for (int q = 0; q < 4; ++q)
            rb[q] = *(const float4*)(bRow + kv0 + sBase + q * 8);
    };

    load_regs(0);
    for (int kt = 0; kt < 12; ++kt) {
        #pragma unroll
        for (int q = 0; q < 4; ++q)
            *(float4*)(&Ast[rS][sBase + q * 8]) = ra[q];
        #pragma unroll
        for (int q = 0; q < 4; ++q)
            *(float4*)(&Bst[rS][sBase + q * 8]) = rb[q];
        __syncthreads();
        if (kt < 11) load_regs(kt + 1);   // overlap next-tile global latency with MFMA
        #pragma unroll
        for (int kk = 0; kk < 2; ++kk) {
            int ko = kk * 32 + (lane >> 4) * 8;
            bf16x8 af[4], bf[4];
            #pragma unroll
            for (int m = 0; m < 4; ++m)
                af[m] = *(const bf16x8*)&Ast[awr + m * 16 + (lane & 15)][ko];
            #pragma unroll
            for (int nn = 0; nn < 4; ++nn)
                bf[nn] = *(const bf16x8*)&Bst[bwc + nn * 16 + (lane & 15)][ko];
            #pragma unroll
            for (int m = 0; m < 4; ++m)
                #pragma unroll
                for (int nn = 0; nn < 4; ++nn)
                    acc[m][nn] = __builtin_amdgcn_mfma_f32_16x16x32_bf16(
                        af[m], bf[nn], acc[m][nn], 0, 0, 0);
        }
        __syncthreads();
    }

    #pragma unroll
    for (int nn = 0; nn < 4; ++nn) {
        int col = colbase + bwc + nn * 16 + (lane & 15);
        float bv = bias[col];
        #pragma unroll
        for (int m = 0; m < 4; ++m) {
            int grow0 = rowbase + awr + m * 16 + ((lane >> 4) << 2);
            f32x4 v = acc[m][nn];
            #pragma unroll
            for (int r = 0; r < 4; ++r) {
                int row = grow0 + r;
                if (row < n) {
                    float val = v[r] + bv;
                    if (RELU) val = fmaxf(val, 0.f);
                    if (BF16OUT)
                        ((ushort*)Cout)[(size_t)row * 256 + col] = f2b(val);
                    else
                        ((float*)Cout)[(size_t)row * 256 + col] = val;
                }
            }
        }
    }
}

// ---------------- final projection: out[i] = h3[i,:] . Wout + bout ----------------
__global__ __launch_bounds__(256) void out_kernel(
    const float* __restrict__ h3, const float* __restrict__ Wout,
    const float* __restrict__ bout, float* __restrict__ out, int n) {
    int node = blockIdx.x * 4 + (threadIdx.x >> 6);
    int lane = threadIdx.x & 63;
    if (node >= n) return;
    float4 v = ((const float4*)(h3 + (size_t)node * 256))[lane];
    float4 w = ((const float4*)Wout)[lane];
    float sum = v.x * w.x + v.y * w.y + v.z * w.z + v.w * w.w;
    #pragma unroll
    for (int d = 32; d > 0; d >>= 1) sum += __shfl_down(sum, d, 64);
    if (lane == 0) out[node] = sum + bout[0];
}

extern "C" void kernel_launch(void* const* d_in, const int* in_sizes, int n_in,
                              void* d_out, int out_size, void* d_ws, size_t ws_size,
                              hipStream_t stream) {
    const int n = NN, e = EE;
    const float* x    = (const float*)d_in[0];
    const int*   eidx = (const int*)d_in[1];
    const float* W1   = (const float*)d_in[2];
    const float* b1   = (const float*)d_in[3];
    const float* Wh   = (const float*)d_in[4];
    const float* bh   = (const float*)d_in[5];
    const float* W2   = (const float*)d_in[6];
    const float* b2   = (const float*)d_in[7];
    const float* Wout = (const float*)d_in[8];
    const float* bout = (const float*)d_in[9];
    const int* row = eidx;        // sources
    const int* col = eidx + e;    // destinations

    char* ws = (char*)d_ws;
    int*    cnt     = (int*)ws;    ws += (size_t)n * 4;
    int*    offs    = (int*)ws;    ws += (size_t)n * 4;
    int*    cursor  = (int*)ws;    ws += (size_t)n * 4;
    float*  dinv    = (float*)ws;  ws += (size_t)n * 4;
    int*    bsum    = (int*)ws;    ws += (size_t)256 * 4;
    int2*   pair    = (int2*)ws;   ws += (size_t)e * 8;
    ushort* hb      = (ushort*)ws; ws += (size_t)n * 256 * 2;   // bf16 hidden state
    ushort* a2      = (ushort*)ws; ws += (size_t)n * 512 * 2;   // A'' hi|lo [n][512]
    ushort* wt1     = (ushort*)ws; ws += (size_t)256 * 768 * 2;
    ushort* wt2     = (ushort*)ws; ws += (size_t)256 * 768 * 2;
    ushort* wt3     = (ushort*)ws; ws += (size_t)256 * 768 * 2;

    float* outv = (float*)d_out;
    float* h3   = (float*)d_out + n;

    int nb_n = (n + 255) / 256;     // 79
    int nb_e = (e + 255) / 256;

    // CSR build
    init_cnt_kernel<<<nb_n, 256, 0, stream>>>(cnt, n);
    hist_kernel<<<nb_e, 256, 0, stream>>>(col, cnt, e);
    dinv_kernel<<<nb_n, 256, 0, stream>>>(cnt, dinv, n);
    scan_p1_kernel<<<nb_n, 256, 0, stream>>>(cnt, offs, bsum, n);
    scan_p2_kernel<<<1, 256, 0, stream>>>(bsum, nb_n);
    scan_p3_kernel<<<nb_n, 256, 0, stream>>>(offs, bsum, cursor, n);
    scatter_kernel<<<nb_e, 256, 0, stream>>>(row, col, dinv, cursor, pair, e);

    // weight prep + x -> bf16
    wprep_kernel<<<256, 256, 0, stream>>>(W1, wt1);
    wprep_kernel<<<256, 256, 0, stream>>>(Wh, wt2);
    wprep_kernel<<<256, 256, 0, stream>>>(W2, wt3);
    cvt_kernel<<<(n * 32 + 255) / 256, 256, 0, stream>>>(x, hb, n * 32);

    int agrid = (n / 4) * 4;           // 20000 blocks: chunk = bid&3, nodegroup = bid>>2
    dim3 ggrid((n + 127) / 128, 2);    // (157, 2)

    // layer 1
    agg_kernel<<<agrid, 256, 0, stream>>>(hb, offs, cnt, pair, dinv, a2, n);
    gemm_mfma_kernel<true, true><<<ggrid, 256, 0, stream>>>(a2, wt1, b1, hb, n);
    // layer 2
    agg_kernel<<<agrid, 256, 0, stream>>>(hb, offs, cnt, pair, dinv, a2, n);
    gemm_mfma_kernel<true, true><<<ggrid, 256, 0, stream>>>(a2, wt2, bh, hb, n);
    // layer 3 -> h3 (f32) straight into d_out
    agg_kernel<<<agrid, 256, 0, stream>>>(hb, offs, cnt, pair, dinv, a2, n);
    gemm_mfma_kernel<false, false><<<ggrid, 256, 0, stream>>>(a2, wt3, b2, h3, n);
    // decoder
    out_kernel<<<(n + 3) / 4, 256, 0, stream>>>(h3, Wout, bout, outv, n);
}

// Round 8
// 395.818 us; speedup vs baseline: 1.6148x; 1.1007x over previous
//
#include <hip/hip_runtime.h>
#include <hip/hip_bf16.h>

#define NN 20000
#define EE 640000

typedef __attribute__((ext_vector_type(8))) short bf16x8;
typedef __attribute__((ext_vector_type(4))) float f32x4;

__device__ __forceinline__ ushort f2b(float f) {
    __hip_bfloat16 h = __float2bfloat16(f);
    return *(ushort*)&h;
}
__device__ __forceinline__ float b2f(ushort u) {
    __hip_bfloat16 h = *(__hip_bfloat16*)&u;
    return __bfloat162float(h);
}

// accumulate 8 bf16 feats (one 16B vector) scaled by m into acc[8]
__device__ __forceinline__ void acc8(float m, bf16x8 v, float* acc) {
    union { bf16x8 v; unsigned u[4]; } t;
    t.v = v;
    #pragma unroll
    for (int k = 0; k < 4; ++k) {
        acc[2 * k]     = fmaf(m, __uint_as_float(t.u[k] << 16), acc[2 * k]);
        acc[2 * k + 1] = fmaf(m, __uint_as_float(t.u[k] & 0xffff0000u), acc[2 * k + 1]);
    }
}

// ---------------- CSR build ----------------

__global__ void init_cnt_kernel(int* __restrict__ cnt, int n) {
    int i = blockIdx.x * 256 + threadIdx.x;
    if (i < n) cnt[i] = 0;
}

__global__ void hist_kernel(const int* __restrict__ col, int* __restrict__ cnt, int e) {
    int i = blockIdx.x * 256 + threadIdx.x;
    if (i < e) atomicAdd(&cnt[col[i]], 1);
}

__global__ void dinv_kernel(const int* __restrict__ cnt, float* __restrict__ dinv, int n) {
    int i = blockIdx.x * 256 + threadIdx.x;
    if (i < n) dinv[i] = rsqrtf((float)(cnt[i] + 1));  // +1 self-loop; always > 0
}

__device__ __forceinline__ int block_exscan(int v) {
    __shared__ int wsum[4];
    int tid = threadIdx.x, lane = tid & 63, w = tid >> 6;
    int x = v;
    #pragma unroll
    for (int d = 1; d < 64; d <<= 1) {
        int y = __shfl_up(x, d, 64);
        if (lane >= d) x += y;
    }
    if (lane == 63) wsum[w] = x;
    __syncthreads();
    if (tid == 0) {
        int s = 0;
        #pragma unroll
        for (int k = 0; k < 4; ++k) { int t = wsum[k]; wsum[k] = s; s += t; }
    }
    __syncthreads();
    return wsum[w] + x - v;
}

__global__ __launch_bounds__(256) void scan_p1_kernel(const int* __restrict__ cnt,
                                                      int* __restrict__ offs,
                                                      int* __restrict__ bsum, int n) {
    int i = blockIdx.x * 256 + threadIdx.x;
    int v = (i < n) ? cnt[i] : 0;
    int e = block_exscan(v);
    if (i < n) offs[i] = e;
    if (threadIdx.x == 255) bsum[blockIdx.x] = e + v;
}

__global__ __launch_bounds__(256) void scan_p2_kernel(int* __restrict__ bsum, int nblk) {
    int t = threadIdx.x;
    int v = (t < nblk) ? bsum[t] : 0;
    int e = block_exscan(v);
    if (t < nblk) bsum[t] = e;
}

__global__ __launch_bounds__(256) void scan_p3_kernel(int* __restrict__ offs,
                                                      const int* __restrict__ bsum,
                                                      int* __restrict__ cursor, int n) {
    int i = blockIdx.x * 256 + threadIdx.x;
    if (i < n) {
        int o = offs[i] + bsum[blockIdx.x];
        offs[i] = o;
        cursor[i] = o;
    }
}

__global__ void scatter_kernel(const int* __restrict__ row, const int* __restrict__ col,
                               const float* __restrict__ dinv, int* __restrict__ cursor,
                               int2* __restrict__ pair, int e) {
    int i = blockIdx.x * 256 + threadIdx.x;
    if (i >= e) return;
    int s = row[i], d = col[i];
    int pos = atomicAdd(&cursor[d], 1);
    int2 p;
    p.x = s;
    p.y = __float_as_int(dinv[s] * dinv[d]);
    pair[pos] = p;
}

// ---------------- x f32 -> bf16 ----------------
__global__ __launch_bounds__(256) void cvt_kernel(const float* __restrict__ x,
                                                  ushort* __restrict__ xb, int total8) {
    int i = blockIdx.x * 256 + threadIdx.x;   // per 8 elements
    if (i >= total8) return;
    float4 a = ((const float4*)x)[2 * i];
    float4 b = ((const float4*)x)[2 * i + 1];
    union { bf16x8 v; ushort s[8]; } o;
    o.s[0] = f2b(a.x); o.s[1] = f2b(a.y); o.s[2] = f2b(a.z); o.s[3] = f2b(a.w);
    o.s[4] = f2b(b.x); o.s[5] = f2b(b.y); o.s[6] = f2b(b.z); o.s[7] = f2b(b.w);
    ((bf16x8*)xb)[i] = o.v;
}

// ---------------- weight prep: W [256][256] f32 -> Wt [256 col][768 kv] bf16 ----------------
__global__ __launch_bounds__(256) void wprep_kernel(const float* __restrict__ W,
                                                    ushort* __restrict__ Wt) {
    int col = blockIdx.x;
    for (int kv = threadIdx.x; kv < 768; kv += 256) {
        int k = kv & 255;
        float w = W[(size_t)k * 256 + col];
        ushort hi = f2b(w);
        ushort out = (kv < 256 || kv >= 512) ? hi : f2b(w - b2f(hi));
        Wt[(size_t)col * 768 + kv] = out;
    }
}

// ---------------- aggregation v7: bf16 gathers, wave per node, 64-feat chunks ----------------
__global__ __launch_bounds__(256) void agg_kernel(
    const ushort* __restrict__ hb,
    const int* __restrict__ offs, const int* __restrict__ cnt,
    const int2* __restrict__ pair,
    const float* __restrict__ dinv,
    ushort* __restrict__ a2, int n) {
    int chunk = blockIdx.x & 3;
    int node = (blockIdx.x >> 2) * 4 + (threadIdx.x >> 6);
    int lane = threadIdx.x & 63;
    int esub = lane >> 3, fsub = lane & 7;
    const ushort* base = hb + chunk * 64 + fsub * 8;
    const unsigned long long* pq = (const unsigned long long*)pair;

    int beg = offs[node], num = cnt[node];
    float acc[8] = {};

    for (int j = 0; j < num; j += 32) {
        int i0 = j + esub, i1 = j + 8 + esub, i2 = j + 16 + esub, i3 = j + 24 + esub;
        bool p0 = i0 < num, p1 = i1 < num, p2 = i2 < num, p3 = i3 < num;
        unsigned long long q0 = pq[p0 ? beg + i0 : beg];
        unsigned long long q1 = pq[p1 ? beg + i1 : beg];
        unsigned long long q2 = pq[p2 ? beg + i2 : beg];
        unsigned long long q3 = pq[p3 ? beg + i3 : beg];
        int s0 = (int)(q0 & 0xffffffffu), s1 = (int)(q1 & 0xffffffffu);
        int s2 = (int)(q2 & 0xffffffffu), s3 = (int)(q3 & 0xffffffffu);
        float m0 = p0 ? __int_as_float((int)(q0 >> 32)) : 0.f;
        float m1 = p1 ? __int_as_float((int)(q1 >> 32)) : 0.f;
        float m2 = p2 ? __int_as_float((int)(q2 >> 32)) : 0.f;
        float m3 = p3 ? __int_as_float((int)(q3 >> 32)) : 0.f;
        bf16x8 v0 = *(const bf16x8*)(base + (size_t)s0 * 256);
        bf16x8 v1 = *(const bf16x8*)(base + (size_t)s1 * 256);
        bf16x8 v2 = *(const bf16x8*)(base + (size_t)s2 * 256);
        bf16x8 v3 = *(const bf16x8*)(base + (size_t)s3 * 256);
        acc8(m0, v0, acc);
        acc8(m1, v1, acc);
        acc8(m2, v2, acc);
        acc8(m3, v3, acc);
    }

    #pragma unroll
    for (int d = 8; d < 64; d <<= 1)
        #pragma unroll
        for (int k = 0; k < 8; ++k)
            acc[k] += __shfl_xor(acc[k], d, 64);

    if (esub == 0) {   // lanes 0..7 hold fsub 0..7
        float di = dinv[node];
        bf16x8 sv = *(const bf16x8*)(base + (size_t)node * 256);
        acc8(di * di, sv, acc);
        int feat = chunk * 64 + fsub * 8;
        union { bf16x8 v; ushort s[8]; } hi, lo;
        #pragma unroll
        for (int k = 0; k < 8; ++k) {
            hi.s[k] = f2b(acc[k]);
            lo.s[k] = f2b(acc[k] - b2f(hi.s[k]));
        }
        *(bf16x8*)(a2 + (size_t)node * 512 + feat)       = hi.v;
        *(bf16x8*)(a2 + (size_t)node * 512 + 256 + feat) = lo.v;
    }
}

// ---------------- LDS-free MFMA GEMM ----------------
// Wave w of block b computes C[b*64 .. +64) x [w*64 .. +64).
// A fragments read straight from a2 (L1/L2), B fragments from Wt (L2-resident 393KB).
// No LDS, no barriers -> compiler free to software-pipeline the fully unrolled K loop.
template<bool RELU, bool BF16OUT>
__global__ __launch_bounds__(256) void gemm_mfma_kernel(
    const ushort* __restrict__ A2, const ushort* __restrict__ Wt,
    const float* __restrict__ bias, void* __restrict__ Cout, int n) {
    int lane = threadIdx.x & 63;
    int wid = threadIdx.x >> 6;
    int rowbase = blockIdx.x * 64;
    int colbase = wid * 64;
    int r = lane & 15;
    int q = lane >> 4;   // 0..3 -> 8-short sub-chunk

    f32x4 zero = {0.f, 0.f, 0.f, 0.f};
    f32x4 acc[4][4];
    #pragma unroll
    for (int m = 0; m < 4; ++m)
        #pragma unroll
        for (int nn = 0; nn < 4; ++nn) acc[m][nn] = zero;

    const ushort* aptr[4];
    #pragma unroll
    for (int m = 0; m < 4; ++m) {
        int row = min(rowbase + m * 16 + r, n - 1);
        aptr[m] = A2 + (size_t)row * 512 + q * 8;
    }
    const ushort* bptr[4];
    #pragma unroll
    for (int nn = 0; nn < 4; ++nn) {
        int col = colbase + nn * 16 + r;
        bptr[nn] = Wt + (size_t)col * 768 + q * 8;
    }

    #pragma unroll
    for (int kt = 0; kt < 12; ++kt) {
        int kv0 = kt * 64;
        int acol0 = (kv0 < 256) ? kv0 : kv0 - 256;
        #pragma unroll
        for (int kk = 0; kk < 2; ++kk) {
            bf16x8 af[4], bf[4];
            #pragma unroll
            for (int m = 0; m < 4; ++m)
                af[m] = *(const bf16x8*)(aptr[m] + acol0 + kk * 32);
            #pragma unroll
            for (int nn = 0; nn < 4; ++nn)
                bf[nn] = *(const bf16x8*)(bptr[nn] + kv0 + kk * 32);
            #pragma unroll
            for (int m = 0; m < 4; ++m)
                #pragma unroll
                for (int nn = 0; nn < 4; ++nn)
                    acc[m][nn] = __builtin_amdgcn_mfma_f32_16x16x32_bf16(
                        af[m], bf[nn], acc[m][nn], 0, 0, 0);
        }
    }

    #pragma unroll
    for (int nn = 0; nn < 4; ++nn) {
        int col = colbase + nn * 16 + r;
        float bv = bias[col];
        #pragma unroll
        for (int m = 0; m < 4; ++m) {
            int grow0 = rowbase + m * 16 + q * 4;
            f32x4 v = acc[m][nn];
            #pragma unroll
            for (int rr = 0; rr < 4; ++rr) {
                int row = grow0 + rr;
                if (row < n) {
                    float val = v[rr] + bv;
                    if (RELU) val = fmaxf(val, 0.f);
                    if (BF16OUT)
                        ((ushort*)Cout)[(size_t)row * 256 + col] = f2b(val);
                    else
                        ((float*)Cout)[(size_t)row * 256 + col] = val;
                }
            }
        }
    }
}

// ---------------- final projection: out[i] = h3[i,:] . Wout + bout ----------------
__global__ __launch_bounds__(256) void out_kernel(
    const float* __restrict__ h3, const float* __restrict__ Wout,
    const float* __restrict__ bout, float* __restrict__ out, int n) {
    int node = blockIdx.x * 4 + (threadIdx.x >> 6);
    int lane = threadIdx.x & 63;
    if (node >= n) return;
    float4 v = ((const float4*)(h3 + (size_t)node * 256))[lane];
    float4 w = ((const float4*)Wout)[lane];
    float sum = v.x * w.x + v.y * w.y + v.z * w.z + v.w * w.w;
    #pragma unroll
    for (int d = 32; d > 0; d >>= 1) sum += __shfl_down(sum, d, 64);
    if (lane == 0) out[node] = sum + bout[0];
}

extern "C" void kernel_launch(void* const* d_in, const int* in_sizes, int n_in,
                              void* d_out, int out_size, void* d_ws, size_t ws_size,
                              hipStream_t stream) {
    const int n = NN, e = EE;
    const float* x    = (const float*)d_in[0];
    const int*   eidx = (const int*)d_in[1];
    const float* W1   = (const float*)d_in[2];
    const float* b1   = (const float*)d_in[3];
    const float* Wh   = (const float*)d_in[4];
    const float* bh   = (const float*)d_in[5];
    const float* W2   = (const float*)d_in[6];
    const float* b2   = (const float*)d_in[7];
    const float* Wout = (const float*)d_in[8];
    const float* bout = (const float*)d_in[9];
    const int* row = eidx;        // sources
    const int* col = eidx + e;    // destinations

    char* ws = (char*)d_ws;
    int*    cnt     = (int*)ws;    ws += (size_t)n * 4;
    int*    offs    = (int*)ws;    ws += (size_t)n * 4;
    int*    cursor  = (int*)ws;    ws += (size_t)n * 4;
    float*  dinv    = (float*)ws;  ws += (size_t)n * 4;
    int*    bsum    = (int*)ws;    ws += (size_t)256 * 4;
    int2*   pair    = (int2*)ws;   ws += (size_t)e * 8;
    ushort* hb      = (ushort*)ws; ws += (size_t)n * 256 * 2;   // bf16 hidden state
    ushort* a2      = (ushort*)ws; ws += (size_t)n * 512 * 2;   // A'' hi|lo [n][512]
    ushort* wt1     = (ushort*)ws; ws += (size_t)256 * 768 * 2;
    ushort* wt2     = (ushort*)ws; ws += (size_t)256 * 768 * 2;
    ushort* wt3     = (ushort*)ws; ws += (size_t)256 * 768 * 2;

    float* outv = (float*)d_out;
    float* h3   = (float*)d_out + n;

    int nb_n = (n + 255) / 256;     // 79
    int nb_e = (e + 255) / 256;

    // CSR build
    init_cnt_kernel<<<nb_n, 256, 0, stream>>>(cnt, n);
    hist_kernel<<<nb_e, 256, 0, stream>>>(col, cnt, e);
    dinv_kernel<<<nb_n, 256, 0, stream>>>(cnt, dinv, n);
    scan_p1_kernel<<<nb_n, 256, 0, stream>>>(cnt, offs, bsum, n);
    scan_p2_kernel<<<1, 256, 0, stream>>>(bsum, nb_n);
    scan_p3_kernel<<<nb_n, 256, 0, stream>>>(offs, bsum, cursor, n);
    scatter_kernel<<<nb_e, 256, 0, stream>>>(row, col, dinv, cursor, pair, e);

    // weight prep + x -> bf16
    wprep_kernel<<<256, 256, 0, stream>>>(W1, wt1);
    wprep_kernel<<<256, 256, 0, stream>>>(Wh, wt2);
    wprep_kernel<<<256, 256, 0, stream>>>(W2, wt3);
    cvt_kernel<<<(n * 32 + 255) / 256, 256, 0, stream>>>(x, hb, n * 32);

    int agrid = (n / 4) * 4;           // 20000 blocks: chunk = bid&3, nodegroup = bid>>2
    int ggrid = (n + 63) / 64;         // 313 blocks x 4 waves (col tiles)

    // layer 1
    agg_kernel<<<agrid, 256, 0, stream>>>(hb, offs, cnt, pair, dinv, a2, n);
    gemm_mfma_kernel<true, true><<<ggrid, 256, 0, stream>>>(a2, wt1, b1, hb, n);
    // layer 2
    agg_kernel<<<agrid, 256, 0, stream>>>(hb, offs, cnt, pair, dinv, a2, n);
    gemm_mfma_kernel<true, true><<<ggrid, 256, 0, stream>>>(a2, wt2, bh, hb, n);
    // layer 3 -> h3 (f32) straight into d_out
    agg_kernel<<<agrid, 256, 0, stream>>>(hb, offs, cnt, pair, dinv, a2, n);
    gemm_mfma_kernel<false, false><<<ggrid, 256, 0, stream>>>(a2, wt3, b2, h3, n);
    // decoder
    out_kernel<<<(n + 3) / 4, 256, 0, stream>>>(h3, Wout, bout, outv, n);
}

// Round 9
// 337.832 us; speedup vs baseline: 1.8919x; 1.1716x over previous
//
#include <hip/hip_runtime.h>
#include <hip/hip_bf16.h>

#define NN 20000
#define EE 640000

typedef __attribute__((ext_vector_type(8))) short bf16x8;
typedef __attribute__((ext_vector_type(4))) float f32x4;

__device__ __forceinline__ ushort f2b(float f) {
    __hip_bfloat16 h = __float2bfloat16(f);
    return *(ushort*)&h;
}
__device__ __forceinline__ float b2f(ushort u) {
    __hip_bfloat16 h = *(__hip_bfloat16*)&u;
    return __bfloat162float(h);
}

// accumulate 8 bf16 feats (one 16B vector) scaled by m into acc[8]
__device__ __forceinline__ void acc8(float m, bf16x8 v, float* acc) {
    union { bf16x8 v; unsigned u[4]; } t;
    t.v = v;
    #pragma unroll
    for (int k = 0; k < 4; ++k) {
        acc[2 * k]     = fmaf(m, __uint_as_float(t.u[k] << 16), acc[2 * k]);
        acc[2 * k + 1] = fmaf(m, __uint_as_float(t.u[k] & 0xffff0000u), acc[2 * k + 1]);
    }
}

// ---------------- CSR build ----------------

__global__ void init_cnt_kernel(int* __restrict__ cnt, int n) {
    int i = blockIdx.x * 256 + threadIdx.x;
    if (i < n) cnt[i] = 0;
}

__global__ void hist_kernel(const int* __restrict__ col, int* __restrict__ cnt, int e) {
    int i = blockIdx.x * 256 + threadIdx.x;
    if (i < e) atomicAdd(&cnt[col[i]], 1);
}

__global__ void dinv_kernel(const int* __restrict__ cnt, float* __restrict__ dinv, int n) {
    int i = blockIdx.x * 256 + threadIdx.x;
    if (i < n) dinv[i] = rsqrtf((float)(cnt[i] + 1));  // +1 self-loop; always > 0
}

__device__ __forceinline__ int block_exscan(int v) {
    __shared__ int wsum[4];
    int tid = threadIdx.x, lane = tid & 63, w = tid >> 6;
    int x = v;
    #pragma unroll
    for (int d = 1; d < 64; d <<= 1) {
        int y = __shfl_up(x, d, 64);
        if (lane >= d) x += y;
    }
    if (lane == 63) wsum[w] = x;
    __syncthreads();
    if (tid == 0) {
        int s = 0;
        #pragma unroll
        for (int k = 0; k < 4; ++k) { int t = wsum[k]; wsum[k] = s; s += t; }
    }
    __syncthreads();
    return wsum[w] + x - v;
}

__global__ __launch_bounds__(256) void scan_p1_kernel(const int* __restrict__ cnt,
                                                      int* __restrict__ offs,
                                                      int* __restrict__ bsum, int n) {
    int i = blockIdx.x * 256 + threadIdx.x;
    int v = (i < n) ? cnt[i] : 0;
    int e = block_exscan(v);
    if (i < n) offs[i] = e;
    if (threadIdx.x == 255) bsum[blockIdx.x] = e + v;
}

__global__ __launch_bounds__(256) void scan_p2_kernel(int* __restrict__ bsum, int nblk) {
    int t = threadIdx.x;
    int v = (t < nblk) ? bsum[t] : 0;
    int e = block_exscan(v);
    if (t < nblk) bsum[t] = e;
}

__global__ __launch_bounds__(256) void scan_p3_kernel(int* __restrict__ offs,
                                                      const int* __restrict__ bsum,
                                                      int* __restrict__ cursor, int n) {
    int i = blockIdx.x * 256 + threadIdx.x;
    if (i < n) {
        int o = offs[i] + bsum[blockIdx.x];
        offs[i] = o;
        cursor[i] = o;
    }
}

__global__ void scatter_kernel(const int* __restrict__ row, const int* __restrict__ col,
                               const float* __restrict__ dinv, int* __restrict__ cursor,
                               int2* __restrict__ pair, int e) {
    int i = blockIdx.x * 256 + threadIdx.x;
    if (i >= e) return;
    int s = row[i], d = col[i];
    int pos = atomicAdd(&cursor[d], 1);
    int2 p;
    p.x = s;
    p.y = __float_as_int(dinv[s] * dinv[d]);
    pair[pos] = p;
}

// ---------------- x f32 -> bf16 ----------------
__global__ __launch_bounds__(256) void cvt_kernel(const float* __restrict__ x,
                                                  ushort* __restrict__ xb, int total8) {
    int i = blockIdx.x * 256 + threadIdx.x;   // per 8 elements
    if (i >= total8) return;
    float4 a = ((const float4*)x)[2 * i];
    float4 b = ((const float4*)x)[2 * i + 1];
    union { bf16x8 v; ushort s[8]; } o;
    o.s[0] = f2b(a.x); o.s[1] = f2b(a.y); o.s[2] = f2b(a.z); o.s[3] = f2b(a.w);
    o.s[4] = f2b(b.x); o.s[5] = f2b(b.y); o.s[6] = f2b(b.z); o.s[7] = f2b(b.w);
    ((bf16x8*)xb)[i] = o.v;
}

// ---------------- weight prep: W [256][256] f32 -> Wt [256 col][768 kv] bf16 ----------------
__global__ __launch_bounds__(256) void wprep_kernel(const float* __restrict__ W,
                                                    ushort* __restrict__ Wt) {
    int col = blockIdx.x;
    for (int kv = threadIdx.x; kv < 768; kv += 256) {
        int k = kv & 255;
        float w = W[(size_t)k * 256 + col];
        ushort hi = f2b(w);
        ushort out = (kv < 256 || kv >= 512) ? hi : f2b(w - b2f(hi));
        Wt[(size_t)col * 768 + kv] = out;
    }
}

// ---------------- aggregation v7: bf16 gathers, wave per node, 64-feat chunks ----------------
__global__ __launch_bounds__(256) void agg_kernel(
    const ushort* __restrict__ hb,
    const int* __restrict__ offs, const int* __restrict__ cnt,
    const int2* __restrict__ pair,
    const float* __restrict__ dinv,
    ushort* __restrict__ a2, int n) {
    int chunk = blockIdx.x & 3;
    int node = (blockIdx.x >> 2) * 4 + (threadIdx.x >> 6);
    int lane = threadIdx.x & 63;
    int esub = lane >> 3, fsub = lane & 7;
    const ushort* base = hb + chunk * 64 + fsub * 8;
    const unsigned long long* pq = (const unsigned long long*)pair;

    int beg = offs[node], num = cnt[node];
    float acc[8] = {};

    for (int j = 0; j < num; j += 32) {
        int i0 = j + esub, i1 = j + 8 + esub, i2 = j + 16 + esub, i3 = j + 24 + esub;
        bool p0 = i0 < num, p1 = i1 < num, p2 = i2 < num, p3 = i3 < num;
        unsigned long long q0 = pq[p0 ? beg + i0 : beg];
        unsigned long long q1 = pq[p1 ? beg + i1 : beg];
        unsigned long long q2 = pq[p2 ? beg + i2 : beg];
        unsigned long long q3 = pq[p3 ? beg + i3 : beg];
        int s0 = (int)(q0 & 0xffffffffu), s1 = (int)(q1 & 0xffffffffu);
        int s2 = (int)(q2 & 0xffffffffu), s3 = (int)(q3 & 0xffffffffu);
        float m0 = p0 ? __int_as_float((int)(q0 >> 32)) : 0.f;
        float m1 = p1 ? __int_as_float((int)(q1 >> 32)) : 0.f;
        float m2 = p2 ? __int_as_float((int)(q2 >> 32)) : 0.f;
        float m3 = p3 ? __int_as_float((int)(q3 >> 32)) : 0.f;
        bf16x8 v0 = *(const bf16x8*)(base + (size_t)s0 * 256);
        bf16x8 v1 = *(const bf16x8*)(base + (size_t)s1 * 256);
        bf16x8 v2 = *(const bf16x8*)(base + (size_t)s2 * 256);
        bf16x8 v3 = *(const bf16x8*)(base + (size_t)s3 * 256);
        acc8(m0, v0, acc);
        acc8(m1, v1, acc);
        acc8(m2, v2, acc);
        acc8(m3, v3, acc);
    }

    #pragma unroll
    for (int d = 8; d < 64; d <<= 1)
        #pragma unroll
        for (int k = 0; k < 8; ++k)
            acc[k] += __shfl_xor(acc[k], d, 64);

    if (esub == 0) {   // lanes 0..7 hold fsub 0..7
        float di = dinv[node];
        bf16x8 sv = *(const bf16x8*)(base + (size_t)node * 256);
        acc8(di * di, sv, acc);
        int feat = chunk * 64 + fsub * 8;
        union { bf16x8 v; ushort s[8]; } hi, lo;
        #pragma unroll
        for (int k = 0; k < 8; ++k) {
            hi.s[k] = f2b(acc[k]);
            lo.s[k] = f2b(acc[k] - b2f(hi.s[k]));
        }
        *(bf16x8*)(a2 + (size_t)node * 512 + feat)       = hi.v;
        *(bf16x8*)(a2 + (size_t)node * 512 + 256 + feat) = lo.v;
    }
}

// ---------------- LDS-free MFMA GEMM, 1 wave/block, 32x64 tile, 2-deep fragment pipeline ----------------
// Wave computes C[bx*32 .. +32) x [by*64 .. +64). n % 32 == 0 -> no row bounds checks.
template<bool RELU, bool BF16OUT>
__global__ __launch_bounds__(64) void gemm_mfma_kernel(
    const ushort* __restrict__ A2, const ushort* __restrict__ Wt,
    const float* __restrict__ bias, void* __restrict__ Cout, int n) {
    int lane = threadIdx.x;
    int rowbase = blockIdx.x * 32;
    int colbase = blockIdx.y * 64;
    int r = lane & 15;
    int q = lane >> 4;   // 0..3 -> 8-short k sub-chunk

    f32x4 zero = {0.f, 0.f, 0.f, 0.f};
    f32x4 acc[2][4];
    #pragma unroll
    for (int m = 0; m < 2; ++m)
        #pragma unroll
        for (int nn = 0; nn < 4; ++nn) acc[m][nn] = zero;

    const ushort* aptr0 = A2 + (size_t)(rowbase + r) * 512 + q * 8;
    const ushort* aptr1 = aptr0 + 16 * 512;
    const ushort* bbase = Wt + (size_t)(colbase + r) * 768 + q * 8;
    const ushort* bptr0 = bbase;
    const ushort* bptr1 = bbase + 16 * 768;
    const ushort* bptr2 = bbase + 32 * 768;
    const ushort* bptr3 = bbase + 48 * 768;

    bf16x8 a0A, a1A, b0A, b1A, b2A, b3A;
    bf16x8 a0B, a1B, b0B, b1B, b2B, b3B;

    auto ldfrag = [&](int s, bf16x8& A0, bf16x8& A1, bf16x8& B0, bf16x8& B1,
                      bf16x8& B2, bf16x8& B3) {
        int kv0 = s * 32;
        int acol = (kv0 < 256) ? kv0 : kv0 - 256;
        A0 = *(const bf16x8*)(aptr0 + acol);
        A1 = *(const bf16x8*)(aptr1 + acol);
        B0 = *(const bf16x8*)(bptr0 + kv0);
        B1 = *(const bf16x8*)(bptr1 + kv0);
        B2 = *(const bf16x8*)(bptr2 + kv0);
        B3 = *(const bf16x8*)(bptr3 + kv0);
    };
    auto domfma = [&](bf16x8& A0, bf16x8& A1, bf16x8& B0, bf16x8& B1,
                      bf16x8& B2, bf16x8& B3) {
        acc[0][0] = __builtin_amdgcn_mfma_f32_16x16x32_bf16(A0, B0, acc[0][0], 0, 0, 0);
        acc[0][1] = __builtin_amdgcn_mfma_f32_16x16x32_bf16(A0, B1, acc[0][1], 0, 0, 0);
        acc[0][2] = __builtin_amdgcn_mfma_f32_16x16x32_bf16(A0, B2, acc[0][2], 0, 0, 0);
        acc[0][3] = __builtin_amdgcn_mfma_f32_16x16x32_bf16(A0, B3, acc[0][3], 0, 0, 0);
        acc[1][0] = __builtin_amdgcn_mfma_f32_16x16x32_bf16(A1, B0, acc[1][0], 0, 0, 0);
        acc[1][1] = __builtin_amdgcn_mfma_f32_16x16x32_bf16(A1, B1, acc[1][1], 0, 0, 0);
        acc[1][2] = __builtin_amdgcn_mfma_f32_16x16x32_bf16(A1, B2, acc[1][2], 0, 0, 0);
        acc[1][3] = __builtin_amdgcn_mfma_f32_16x16x32_bf16(A1, B3, acc[1][3], 0, 0, 0);
    };

    ldfrag(0, a0A, a1A, b0A, b1A, b2A, b3A);
    #pragma unroll
    for (int s = 0; s < 24; s += 2) {
        ldfrag(s + 1, a0B, a1B, b0B, b1B, b2B, b3B);
        domfma(a0A, a1A, b0A, b1A, b2A, b3A);
        if (s + 2 < 24) ldfrag(s + 2, a0A, a1A, b0A, b1A, b2A, b3A);
        domfma(a0B, a1B, b0B, b1B, b2B, b3B);
    }

    #pragma unroll
    for (int nn = 0; nn < 4; ++nn) {
        int col = colbase + nn * 16 + r;
        float bv = bias[col];
        #pragma unroll
        for (int m = 0; m < 2; ++m) {
            int grow0 = rowbase + m * 16 + q * 4;
            f32x4 v = acc[m][nn];
            #pragma unroll
            for (int rr = 0; rr < 4; ++rr) {
                int row = grow0 + rr;
                float val = v[rr] + bv;
                if (RELU) val = fmaxf(val, 0.f);
                if (BF16OUT)
                    ((ushort*)Cout)[(size_t)row * 256 + col] = f2b(val);
                else
                    ((float*)Cout)[(size_t)row * 256 + col] = val;
            }
        }
    }
}

// ---------------- final projection: out[i] = h3[i,:] . Wout + bout ----------------
__global__ __launch_bounds__(256) void out_kernel(
    const float* __restrict__ h3, const float* __restrict__ Wout,
    const float* __restrict__ bout, float* __restrict__ out, int n) {
    int node = blockIdx.x * 4 + (threadIdx.x >> 6);
    int lane = threadIdx.x & 63;
    if (node >= n) return;
    float4 v = ((const float4*)(h3 + (size_t)node * 256))[lane];
    float4 w = ((const float4*)Wout)[lane];
    float sum = v.x * w.x + v.y * w.y + v.z * w.z + v.w * w.w;
    #pragma unroll
    for (int d = 32; d > 0; d >>= 1) sum += __shfl_down(sum, d, 64);
    if (lane == 0) out[node] = sum + bout[0];
}

extern "C" void kernel_launch(void* const* d_in, const int* in_sizes, int n_in,
                              void* d_out, int out_size, void* d_ws, size_t ws_size,
                              hipStream_t stream) {
    const int n = NN, e = EE;
    const float* x    = (const float*)d_in[0];
    const int*   eidx = (const int*)d_in[1];
    const float* W1   = (const float*)d_in[2];
    const float* b1   = (const float*)d_in[3];
    const float* Wh   = (const float*)d_in[4];
    const float* bh   = (const float*)d_in[5];
    const float* W2   = (const float*)d_in[6];
    const float* b2   = (const float*)d_in[7];
    const float* Wout = (const float*)d_in[8];
    const float* bout = (const float*)d_in[9];
    const int* row = eidx;        // sources
    const int* col = eidx + e;    // destinations

    char* ws = (char*)d_ws;
    int*    cnt     = (int*)ws;    ws += (size_t)n * 4;
    int*    offs    = (int*)ws;    ws += (size_t)n * 4;
    int*    cursor  = (int*)ws;    ws += (size_t)n * 4;
    float*  dinv    = (float*)ws;  ws += (size_t)n * 4;
    int*    bsum    = (int*)ws;    ws += (size_t)256 * 4;
    int2*   pair    = (int2*)ws;   ws += (size_t)e * 8;
    ushort* hb      = (ushort*)ws; ws += (size_t)n * 256 * 2;   // bf16 hidden state
    ushort* a2      = (ushort*)ws; ws += (size_t)n * 512 * 2;   // A'' hi|lo [n][512]
    ushort* wt1     = (ushort*)ws; ws += (size_t)256 * 768 * 2;
    ushort* wt2     = (ushort*)ws; ws += (size_t)256 * 768 * 2;
    ushort* wt3     = (ushort*)ws; ws += (size_t)256 * 768 * 2;

    float* outv = (float*)d_out;
    float* h3   = (float*)d_out + n;

    int nb_n = (n + 255) / 256;     // 79
    int nb_e = (e + 255) / 256;

    // CSR build
    init_cnt_kernel<<<nb_n, 256, 0, stream>>>(cnt, n);
    hist_kernel<<<nb_e, 256, 0, stream>>>(col, cnt, e);
    dinv_kernel<<<nb_n, 256, 0, stream>>>(cnt, dinv, n);
    scan_p1_kernel<<<nb_n, 256, 0, stream>>>(cnt, offs, bsum, n);
    scan_p2_kernel<<<1, 256, 0, stream>>>(bsum, nb_n);
    scan_p3_kernel<<<nb_n, 256, 0, stream>>>(offs, bsum, cursor, n);
    scatter_kernel<<<nb_e, 256, 0, stream>>>(row, col, dinv, cursor, pair, e);

    // weight prep + x -> bf16
    wprep_kernel<<<256, 256, 0, stream>>>(W1, wt1);
    wprep_kernel<<<256, 256, 0, stream>>>(Wh, wt2);
    wprep_kernel<<<256, 256, 0, stream>>>(W2, wt3);
    cvt_kernel<<<(n * 32 + 255) / 256, 256, 0, stream>>>(x, hb, n * 32);

    int agrid = (n / 4) * 4;            // 20000 blocks: chunk = bid&3, nodegroup = bid>>2
    dim3 ggrid(n / 32, 4);              // (625, 4) = 2500 one-wave blocks

    // layer 1
    agg_kernel<<<agrid, 256, 0, stream>>>(hb, offs, cnt, pair, dinv, a2, n);
    gemm_mfma_kernel<true, true><<<ggrid, 64, 0, stream>>>(a2, wt1, b1, hb, n);
    // layer 2
    agg_kernel<<<agrid, 256, 0, stream>>>(hb, offs, cnt, pair, dinv, a2, n);
    gemm_mfma_kernel<true, true><<<ggrid, 64, 0, stream>>>(a2, wt2, bh, hb, n);
    // layer 3 -> h3 (f32) straight into d_out
    agg_kernel<<<agrid, 256, 0, stream>>>(hb, offs, cnt, pair, dinv, a2, n);
    gemm_mfma_kernel<false, false><<<ggrid, 64, 0, stream>>>(a2, wt3, b2, h3, n);
    // decoder
    out_kernel<<<(n + 3) / 4, 256, 0, stream>>>(h3, Wout, bout, outv, n);
}